// Round 1
// baseline (49.551 us; speedup 1.0000x reference)
//
#include <hip/hip_runtime.h>

static constexpr int Bn = 256;
static constexpr int Ln = 4096;
static constexpr int Dn = 40;     // output dim
static constexpr int NU = 101;    // number of embedding rows
static constexpr float PADF = 39.0f;

// Kernel 0: renormalize table (max_norm=1) + per-unit argmax label.
__global__ __launch_bounds__(128) void prep_kernel(const float* __restrict__ W,
                                                   float* __restrict__ Wsc,
                                                   int* __restrict__ lab) {
    int u = threadIdx.x;
    if (u >= NU) return;
    float row[Dn];
    float ss = 0.f;
#pragma unroll
    for (int d = 0; d < Dn; ++d) { float v = W[u * Dn + d]; row[d] = v; ss += v * v; }
    float nrm = sqrtf(ss);
    float scale = fminf(1.0f, 1.0f / fmaxf(nrm, 1e-12f));
    float best = -3.4e38f; int bi = 0;
#pragma unroll
    for (int d = 0; d < Dn; ++d) {
        float v = row[d] * scale;
        Wsc[u * Dn + d] = v;
        if (v > best) { best = v; bi = d; }   // strict > == jnp first-max tie-break
    }
    lab[u] = bi;
}

// Kernel 1: probs[b,l,:] = Wsc[x[b,l]] — LDS table, coalesced float4 stores.
// Work item g indexes float4 #g of the output: position p = g/10, chunk c = g%10.
__global__ __launch_bounds__(256) void probs_kernel(const int* __restrict__ x,
                                                    const float4* __restrict__ Wsc4,
                                                    float4* __restrict__ out) {
    __shared__ float4 w[NU * 10];
    for (int i = threadIdx.x; i < NU * 10; i += 256) w[i] = Wsc4[i];
    __syncthreads();
    const int total = Bn * Ln * 10;
    const int stride = gridDim.x * 256;
    for (int g = blockIdx.x * 256 + threadIdx.x; g < total; g += stride) {
        int p = g / 10;            // compiler lowers to magic-mul
        int c = g - p * 10;
        int u = x[p];              // 10 threads share p -> L1 broadcast
        out[g] = w[u * 10 + c];
    }
}

// Kernel 2: per-row labels, run-length inv, labels_ded. One block per row,
// 256 threads x 16 positions. Wave shfl-scan + cross-wave LDS scan.
__global__ __launch_bounds__(256) void rle_kernel(const int* __restrict__ x,
                                                  const int* __restrict__ lab,
                                                  float* __restrict__ labels,
                                                  float* __restrict__ ded,
                                                  float* __restrict__ inv) {
    __shared__ int slab[NU];
    __shared__ int wsum[4];
    const int tid = threadIdx.x;
    const int row = blockIdx.x;
    for (int i = tid; i < NU; i += 256) slab[i] = lab[i];
    __syncthreads();

    const int* xr = x + row * Ln;
    const int t0 = tid * 16;

    int xv[16];
    const int4* xp = (const int4*)(xr + t0);
#pragma unroll
    for (int q = 0; q < 4; ++q) {
        int4 a = xp[q];
        xv[q * 4 + 0] = a.x; xv[q * 4 + 1] = a.y;
        xv[q * 4 + 2] = a.z; xv[q * 4 + 3] = a.w;
    }
    const int prevlab = (tid == 0) ? -1 : slab[xr[t0 - 1]];  // -1 => first always keeps

    int lv[16]; int invloc[16];
    int run = prevlab; int cnt = 0;
#pragma unroll
    for (int j = 0; j < 16; ++j) {
        lv[j] = slab[xv[j]];
        cnt += (lv[j] != run) ? 1 : 0;
        invloc[j] = cnt;           // inclusive keep-count within chunk
        run = lv[j];
    }

    // inclusive scan of cnt across the 64-lane wave
    const int lane = tid & 63;
    const int wid = tid >> 6;
    int incl = cnt;
#pragma unroll
    for (int off = 1; off < 64; off <<= 1) {
        int v = __shfl_up(incl, off, 64);
        if (lane >= off) incl += v;
    }
    if (lane == 63) wsum[wid] = incl;
    __syncthreads();
    int waveoff = 0;
    for (int w = 0; w < wid; ++w) waveoff += wsum[w];
    const int excl = waveoff + incl - cnt;   // keeps strictly before this chunk

    float* lrow = labels + row * Ln + t0;
    float* irow = inv + row * Ln + t0;
    float* drow = ded + row * Ln;

    float lb[16], iv[16];
#pragma unroll
    for (int j = 0; j < 16; ++j) {
        lb[j] = (float)lv[j];
        iv[j] = (float)(excl + invloc[j] - 1);
    }
#pragma unroll
    for (int q = 0; q < 4; ++q) {
        ((float4*)lrow)[q] = make_float4(lb[q*4], lb[q*4+1], lb[q*4+2], lb[q*4+3]);
        ((float4*)irow)[q] = make_float4(iv[q*4], iv[q*4+1], iv[q*4+2], iv[q*4+3]);
        ((float4*)(drow + t0))[q] = make_float4(PADF, PADF, PADF, PADF);
    }
    __syncthreads();   // PAD init complete before scatter of run-start values

    run = prevlab; int c2 = 0;
#pragma unroll
    for (int j = 0; j < 16; ++j) {
        if (lv[j] != run) {
            drow[excl + c2] = (float)lv[j];
            ++c2;
        }
        run = lv[j];
    }
}

extern "C" void kernel_launch(void* const* d_in, const int* in_sizes, int n_in,
                              void* d_out, int out_size, void* d_ws, size_t ws_size,
                              hipStream_t stream) {
    const int* x = (const int*)d_in[0];        // [256,4096] int32
    const float* W = (const float*)d_in[1];    // [101,40] f32

    float* out = (float*)d_out;
    float* probs  = out;                                  // 256*4096*40
    float* labels = out + (size_t)Bn * Ln * Dn;           // 256*4096
    float* ded    = labels + (size_t)Bn * Ln;             // 256*4096
    float* inv    = ded + (size_t)Bn * Ln;                // 256*4096

    float* Wsc = (float*)d_ws;                            // 101*40 f32 (16160 B)
    int* lab = (int*)((char*)d_ws + 16384);               // 101 int

    prep_kernel<<<1, 128, 0, stream>>>(W, Wsc, lab);
    probs_kernel<<<2048, 256, 0, stream>>>(x, (const float4*)Wsc, (float4*)probs);
    rle_kernel<<<Bn, 256, 0, stream>>>(x, lab, labels, ded, inv);
}

// Round 2
// 43.865 us; speedup vs baseline: 1.1296x; 1.1296x over previous
//
#include <hip/hip_runtime.h>

static constexpr int Bn = 256;
static constexpr int Ln = 4096;
static constexpr int Dn = 40;     // output dim
static constexpr int NU = 101;    // number of embedding rows
static constexpr float PADF = 39.0f;
static constexpr int PROBS_BLOCKS = 2048;
static constexpr int TOTAL_BLOCKS = PROBS_BLOCKS + Bn;   // 2304

// One fused kernel, heterogeneous block roles:
//   blocks [0, Bn)            : RLE role — one output row each (labels/ded/inv)
//   blocks [Bn, Bn+PROBS_BLOCKS): probs role — grid-stride float4 broadcast-gather
// Every block recomputes what it needs from the tiny 101x40 table (L2-resident
// after the first readers), so there is no producer kernel and no serialization.
__global__ __launch_bounds__(256) void fused_kernel(const int* __restrict__ x,
                                                    const float* __restrict__ W,
                                                    float* __restrict__ out) {
    __shared__ float sW[NU * Dn];     // probs role: scaled table
    __shared__ int slab[NU];          // rle role: per-unit argmax label
    __shared__ int wsum[4];

    float* probs  = out;
    float* labels = out + (size_t)Bn * Ln * Dn;
    float* ded    = labels + (size_t)Bn * Ln;
    float* inv    = ded + (size_t)Bn * Ln;

    const int tid = threadIdx.x;
    const int bid = blockIdx.x;

    if (bid >= Bn) {
        // ---------------- probs role ----------------
        float4* sW4 = (float4*)sW;
        const float4* W4 = (const float4*)W;          // 16160 B, 16B-aligned
        for (int i = tid; i < NU * Dn / 4; i += 256) sW4[i] = W4[i];
        __syncthreads();
        if (tid < NU) {
            float ss = 0.f;
#pragma unroll
            for (int d = 0; d < Dn; ++d) { float v = sW[tid * Dn + d]; ss += v * v; }
            float scale = fminf(1.0f, 1.0f / fmaxf(sqrtf(ss), 1e-12f));
#pragma unroll
            for (int d = 0; d < Dn; ++d) sW[tid * Dn + d] *= scale;
        }
        __syncthreads();

        const int total = Bn * Ln * 10;               // float4 count
        const int stride = PROBS_BLOCKS * 256;
        float4* out4 = (float4*)probs;
        for (int g = (bid - Bn) * 256 + tid; g < total; g += stride) {
            int p = g / 10;                            // magic-mul
            int c = g - p * 10;
            int u = x[p];                              // 10 threads share p -> cache hit
            out4[g] = sW4[u * 10 + c];
        }
    } else {
        // ---------------- rle role (row = bid) ----------------
        if (tid < NU) {
            const float* wr = W + tid * Dn;
            float ss = 0.f;
#pragma unroll
            for (int d = 0; d < Dn; ++d) { float v = wr[d]; ss += v * v; }
            float scale = fminf(1.0f, 1.0f / fmaxf(sqrtf(ss), 1e-12f));
            float best = -3.4e38f; int bi = 0;
#pragma unroll
            for (int d = 0; d < Dn; ++d) {
                float v = wr[d] * scale;               // argmax on SCALED values (ties!)
                if (v > best) { best = v; bi = d; }    // strict > == jnp first-max
            }
            slab[tid] = bi;
        }
        __syncthreads();

        const int row = bid;
        const int* xr = x + row * Ln;
        const int t0 = tid * 16;

        int xv[16];
        const int4* xp = (const int4*)(xr + t0);
#pragma unroll
        for (int q = 0; q < 4; ++q) {
            int4 a = xp[q];
            xv[q * 4 + 0] = a.x; xv[q * 4 + 1] = a.y;
            xv[q * 4 + 2] = a.z; xv[q * 4 + 3] = a.w;
        }
        const int prevlab = (tid == 0) ? -1 : slab[xr[t0 - 1]];

        int lv[16]; int invloc[16];
        int run = prevlab; int cnt = 0;
#pragma unroll
        for (int j = 0; j < 16; ++j) {
            lv[j] = slab[xv[j]];
            cnt += (lv[j] != run) ? 1 : 0;
            invloc[j] = cnt;
            run = lv[j];
        }

        const int lane = tid & 63;
        const int wid = tid >> 6;
        int incl = cnt;
#pragma unroll
        for (int off = 1; off < 64; off <<= 1) {
            int v = __shfl_up(incl, off, 64);
            if (lane >= off) incl += v;
        }
        if (lane == 63) wsum[wid] = incl;
        __syncthreads();
        int waveoff = 0;
        for (int w = 0; w < wid; ++w) waveoff += wsum[w];
        const int excl = waveoff + incl - cnt;

        float* lrow = labels + row * Ln + t0;
        float* irow = inv + row * Ln + t0;
        float* drow = ded + row * Ln;

        float lb[16], iv[16];
#pragma unroll
        for (int j = 0; j < 16; ++j) {
            lb[j] = (float)lv[j];
            iv[j] = (float)(excl + invloc[j] - 1);
        }
#pragma unroll
        for (int q = 0; q < 4; ++q) {
            ((float4*)lrow)[q] = make_float4(lb[q*4], lb[q*4+1], lb[q*4+2], lb[q*4+3]);
            ((float4*)irow)[q] = make_float4(iv[q*4], iv[q*4+1], iv[q*4+2], iv[q*4+3]);
            ((float4*)(drow + t0))[q] = make_float4(PADF, PADF, PADF, PADF);
        }
        __syncthreads();   // PAD init complete before run-start scatter

        run = prevlab; int c2 = 0;
#pragma unroll
        for (int j = 0; j < 16; ++j) {
            if (lv[j] != run) {
                drow[excl + c2] = (float)lv[j];
                ++c2;
            }
            run = lv[j];
        }
    }
}

extern "C" void kernel_launch(void* const* d_in, const int* in_sizes, int n_in,
                              void* d_out, int out_size, void* d_ws, size_t ws_size,
                              hipStream_t stream) {
    const int* x = (const int*)d_in[0];        // [256,4096] int32
    const float* W = (const float*)d_in[1];    // [101,40] f32
    float* out = (float*)d_out;

    fused_kernel<<<TOTAL_BLOCKS, 256, 0, stream>>>(x, W, out);
}

// Round 3
// 37.531 us; speedup vs baseline: 1.3203x; 1.1688x over previous
//
#include <hip/hip_runtime.h>

static constexpr int Bn = 256;
static constexpr int Ln = 4096;
static constexpr int Dn = 40;     // output dim
static constexpr int NU = 101;    // number of embedding rows
static constexpr float PADF = 39.0f;

static constexpr int NBLK = 2048;                    // exactly 8 blocks/CU of work
static constexpr int T_F4 = Bn * Ln * (Dn / 4);      // 10,485,760 float4s of probs
static constexpr int Q_PROBS = 5184;                 // f4 per pure-probs block
static constexpr int Q_RLE   = 4672;                 // f4 per rle block (~2 iter less)
static_assert((NBLK - Bn) * Q_PROBS + Bn * Q_RLE == T_F4, "probs split must cover exactly");

static constexpr int SMEM_BYTES = 18432;

// One fused kernel, 2048 blocks:
//   blocks [0, Bn)    : RLE for row bid (labels/ded/inv), then a reduced probs share
//   blocks [Bn, 2048) : probs share only
// All per-block probs ranges are contiguous; x ids staged in LDS; ded staged in LDS.
__global__ __launch_bounds__(256) void fused_kernel(const int* __restrict__ x,
                                                    const float* __restrict__ W,
                                                    float* __restrict__ out) {
    __shared__ __align__(16) char smem[SMEM_BYTES];
    // probs-phase layout:
    float4* sW4 = (float4*)smem;                     // 1010 f4 = 16160 B (scaled table)
    float*  sW  = (float*)smem;
    int*    sx  = (int*)(smem + 16160);              // up to 568 ints (needs <= 521)
    // rle-phase layout (aliased; phases separated by barriers):
    float*  sded  = (float*)smem;                    // 4096 f32 = 16384 B
    float4* sded4 = (float4*)smem;
    int*    slab  = (int*)(smem + 16384);            // 101 ints
    int*    wsum  = (int*)(smem + 16384 + 101 * 4);  // 4 ints

    float* probs  = out;
    float* labels = out + (size_t)Bn * Ln * Dn;
    float* ded    = labels + (size_t)Bn * Ln;
    float* inv    = ded + (size_t)Bn * Ln;

    const int tid = threadIdx.x;
    const int bid = blockIdx.x;

    int start, len;
    if (bid < Bn) {
        // ================= RLE phase (row = bid) =================
        start = (NBLK - Bn) * Q_PROBS + bid * Q_RLE;
        len = Q_RLE;

        if (tid < NU) {
            const float* wr = W + tid * Dn;
            float ss = 0.f;
#pragma unroll
            for (int d = 0; d < Dn; ++d) { float v = wr[d]; ss += v * v; }
            float scale = fminf(1.0f, 1.0f / fmaxf(sqrtf(ss), 1e-12f));
            float best = -3.4e38f; int bi = 0;
#pragma unroll
            for (int d = 0; d < Dn; ++d) {
                float v = wr[d] * scale;               // argmax on SCALED values
                if (v > best) { best = v; bi = d; }    // strict > == jnp first-max
            }
            slab[tid] = bi;
        }
        {
            const float4 padv = make_float4(PADF, PADF, PADF, PADF);
            for (int i = tid; i < Ln / 4; i += 256) sded4[i] = padv;
        }
        __syncthreads();

        const int row = bid;
        const int* xr = x + row * Ln;
        const int t0 = tid * 16;

        int xv[16];
        const int4* xp = (const int4*)(xr + t0);
#pragma unroll
        for (int q = 0; q < 4; ++q) {
            int4 a = xp[q];
            xv[q * 4 + 0] = a.x; xv[q * 4 + 1] = a.y;
            xv[q * 4 + 2] = a.z; xv[q * 4 + 3] = a.w;
        }
        const int prevlab = (tid == 0) ? -1 : slab[xr[t0 - 1]];

        int lv[16]; int invloc[16];
        int run = prevlab; int cnt = 0;
#pragma unroll
        for (int j = 0; j < 16; ++j) {
            lv[j] = slab[xv[j]];
            cnt += (lv[j] != run) ? 1 : 0;
            invloc[j] = cnt;
            run = lv[j];
        }

        const int lane = tid & 63;
        const int wid = tid >> 6;
        int incl = cnt;
#pragma unroll
        for (int off = 1; off < 64; off <<= 1) {
            int v = __shfl_up(incl, off, 64);
            if (lane >= off) incl += v;
        }
        if (lane == 63) wsum[wid] = incl;
        __syncthreads();
        int waveoff = 0;
        for (int w = 0; w < wid; ++w) waveoff += wsum[w];
        const int excl = waveoff + incl - cnt;

        float* lrow = labels + row * Ln + t0;
        float* irow = inv + row * Ln + t0;

        float lb[16], iv[16];
#pragma unroll
        for (int j = 0; j < 16; ++j) {
            lb[j] = (float)lv[j];
            iv[j] = (float)(excl + invloc[j] - 1);
        }
#pragma unroll
        for (int q = 0; q < 4; ++q) {
            ((float4*)lrow)[q] = make_float4(lb[q*4], lb[q*4+1], lb[q*4+2], lb[q*4+3]);
            ((float4*)irow)[q] = make_float4(iv[q*4], iv[q*4+1], iv[q*4+2], iv[q*4+3]);
        }

        // scatter run-start values into LDS ded row
        run = prevlab; int c2 = 0;
#pragma unroll
        for (int j = 0; j < 16; ++j) {
            if (lv[j] != run) {
                sded[excl + c2] = (float)lv[j];
                ++c2;
            }
            run = lv[j];
        }
        __syncthreads();
        // coalesced writeout of the ded row
        float4* drow4 = (float4*)(ded + row * Ln);
        for (int i = tid; i < Ln / 4; i += 256) drow4[i] = sded4[i];
        __syncthreads();   // LDS about to be reused by probs phase
    } else {
        start = (bid - Bn) * Q_PROBS;
        len = Q_PROBS;
    }

    // ================= probs phase (all blocks) =================
    {
        const float4* W4 = (const float4*)W;
        for (int i = tid; i < NU * Dn / 4; i += 256) sW4[i] = W4[i];
        __syncthreads();
        if (tid < NU) {
            float ss = 0.f;
#pragma unroll
            for (int d = 0; d < Dn; ++d) { float v = sW[tid * Dn + d]; ss += v * v; }
            float scale = fminf(1.0f, 1.0f / fmaxf(sqrtf(ss), 1e-12f));
#pragma unroll
            for (int d = 0; d < Dn; ++d) sW[tid * Dn + d] *= scale;
        }
        const int pbase = start / 10;
        const int pend = (start + len - 1) / 10;
        const int pcnt = pend - pbase + 1;           // <= 520
        for (int i = tid; i < pcnt; i += 256) sx[i] = x[pbase + i];
        __syncthreads();

        float4* out4 = (float4*)probs;
        const int end = start + len;
        for (int idx = start + tid; idx < end; idx += 256) {
            int p = idx / 10;                        // magic-mul
            int c = idx - p * 10;
            int u = sx[p - pbase];                   // LDS broadcast (10 lanes share)
            out4[idx] = sW4[u * 10 + c];
        }
    }
}

extern "C" void kernel_launch(void* const* d_in, const int* in_sizes, int n_in,
                              void* d_out, int out_size, void* d_ws, size_t ws_size,
                              hipStream_t stream) {
    const int* x = (const int*)d_in[0];        // [256,4096] int32
    const float* W = (const float*)d_in[1];    // [101,40] f32
    float* out = (float*)d_out;

    fused_kernel<<<NBLK, 256, 0, stream>>>(x, W, out);
}

// Round 4
// 37.246 us; speedup vs baseline: 1.3304x; 1.0076x over previous
//
#include <hip/hip_runtime.h>

static constexpr int Bn = 256;
static constexpr int Ln = 4096;
static constexpr int Dn = 40;     // output dim
static constexpr int NU = 101;    // number of embedding rows
static constexpr float PADF = 39.0f;

static constexpr int NBLK = 2048;        // 8 blocks/CU, all co-resident
static constexpr int P_PROBS = 560;      // positions per pure-probs block
static constexpr int P_RLE   = 176;      // positions per rle block (~64KB less = their extra RLE traffic)
static_assert((NBLK - Bn) * P_PROBS + Bn * P_RLE == Bn * Ln, "position split must cover exactly");

static constexpr int SMEM_BYTES = 18432;

// One fused kernel, 2048 blocks:
//   blocks [0, Bn)    : RLE for row bid (labels/ded/inv), then small probs share
//   blocks [Bn, 2048) : probs share only
// probs inner loop: 250 active threads, thread = (pl, c) = (tid/10, tid%10) hoisted;
// per iter: u = sx[kk*25+pl] (LDS broadcast), store sW4[u*10+c] -> contiguous f4 stream.
__global__ __launch_bounds__(256) void fused_kernel(const int* __restrict__ x,
                                                    const float* __restrict__ W,
                                                    float* __restrict__ out) {
    __shared__ __align__(16) char smem[SMEM_BYTES];
    // probs-phase layout:
    float4* sW4 = (float4*)smem;                     // 1010 f4 = 16160 B (scaled table)
    float*  sW  = (float*)smem;
    int*    sx  = (int*)(smem + 16160);              // up to 568 ints (needs <= 560)
    // rle-phase layout (aliased; phases separated by barriers):
    float*  sded  = (float*)smem;                    // 4096 f32 = 16384 B
    float4* sded4 = (float4*)smem;
    int*    slab  = (int*)(smem + 16384);            // 101 ints
    int*    wsum  = (int*)(smem + 16384 + 101 * 4);  // 4 ints

    float* probs  = out;
    float* labels = out + (size_t)Bn * Ln * Dn;
    float* ded    = labels + (size_t)Bn * Ln;
    float* inv    = ded + (size_t)Bn * Ln;

    const int tid = threadIdx.x;
    const int bid = blockIdx.x;

    int pbase, pcnt;
    if (bid < Bn) {
        // ================= RLE phase (row = bid) =================
        pbase = (NBLK - Bn) * P_PROBS + bid * P_RLE;
        pcnt = P_RLE;

        if (tid < NU) {
            const float* wr = W + tid * Dn;
            float ss = 0.f;
#pragma unroll
            for (int d = 0; d < Dn; ++d) { float v = wr[d]; ss += v * v; }
            float scale = fminf(1.0f, 1.0f / fmaxf(sqrtf(ss), 1e-12f));
            float best = -3.4e38f; int bi = 0;
#pragma unroll
            for (int d = 0; d < Dn; ++d) {
                float v = wr[d] * scale;               // argmax on SCALED values
                if (v > best) { best = v; bi = d; }    // strict > == jnp first-max
            }
            slab[tid] = bi;
        }
        {
            const float4 padv = make_float4(PADF, PADF, PADF, PADF);
            for (int i = tid; i < Ln / 4; i += 256) sded4[i] = padv;
        }
        __syncthreads();

        const int row = bid;
        const int* xr = x + row * Ln;
        const int t0 = tid * 16;

        int xv[16];
        const int4* xp = (const int4*)(xr + t0);
#pragma unroll
        for (int q = 0; q < 4; ++q) {
            int4 a = xp[q];
            xv[q * 4 + 0] = a.x; xv[q * 4 + 1] = a.y;
            xv[q * 4 + 2] = a.z; xv[q * 4 + 3] = a.w;
        }
        const int prevlab = (tid == 0) ? -1 : slab[xr[t0 - 1]];

        int lv[16]; int invloc[16];
        int run = prevlab; int cnt = 0;
#pragma unroll
        for (int j = 0; j < 16; ++j) {
            lv[j] = slab[xv[j]];
            cnt += (lv[j] != run) ? 1 : 0;
            invloc[j] = cnt;
            run = lv[j];
        }

        const int lane = tid & 63;
        const int wid = tid >> 6;
        int incl = cnt;
#pragma unroll
        for (int off = 1; off < 64; off <<= 1) {
            int v = __shfl_up(incl, off, 64);
            if (lane >= off) incl += v;
        }
        if (lane == 63) wsum[wid] = incl;
        __syncthreads();
        int waveoff = 0;
        for (int w = 0; w < wid; ++w) waveoff += wsum[w];
        const int excl = waveoff + incl - cnt;

        float* lrow = labels + row * Ln + t0;
        float* irow = inv + row * Ln + t0;

        float lb[16], iv[16];
#pragma unroll
        for (int j = 0; j < 16; ++j) {
            lb[j] = (float)lv[j];
            iv[j] = (float)(excl + invloc[j] - 1);
        }
#pragma unroll
        for (int q = 0; q < 4; ++q) {
            ((float4*)lrow)[q] = make_float4(lb[q*4], lb[q*4+1], lb[q*4+2], lb[q*4+3]);
            ((float4*)irow)[q] = make_float4(iv[q*4], iv[q*4+1], iv[q*4+2], iv[q*4+3]);
        }

        // scatter run-start values into LDS ded row
        run = prevlab; int c2 = 0;
#pragma unroll
        for (int j = 0; j < 16; ++j) {
            if (lv[j] != run) {
                sded[excl + c2] = (float)lv[j];
                ++c2;
            }
            run = lv[j];
        }
        __syncthreads();
        // coalesced writeout of the ded row
        float4* drow4 = (float4*)(ded + row * Ln);
        for (int i = tid; i < Ln / 4; i += 256) drow4[i] = sded4[i];
        __syncthreads();   // LDS about to be reused by probs phase
    } else {
        pbase = (bid - Bn) * P_PROBS;
        pcnt = P_PROBS;
    }

    // ================= probs phase (all blocks) =================
    {
        const float4* W4 = (const float4*)W;
        for (int i = tid; i < NU * Dn / 4; i += 256) sW4[i] = W4[i];
        for (int i = tid; i < pcnt; i += 256) sx[i] = x[pbase + i];
        __syncthreads();
        if (tid < NU) {
            float ss = 0.f;
#pragma unroll
            for (int d = 0; d < Dn; ++d) { float v = sW[tid * Dn + d]; ss += v * v; }
            float scale = fminf(1.0f, 1.0f / fmaxf(sqrtf(ss), 1e-12f));
#pragma unroll
            for (int d = 0; d < Dn; ++d) sW[tid * Dn + d] *= scale;
        }
        __syncthreads();

        if (tid < 250) {
            const int pl = tid / 10;                 // 0..24, loop-invariant
            const int c  = tid - pl * 10;            // 0..9,  loop-invariant
            float4* outp = (float4*)probs + (size_t)pbase * 10 + tid;
            const int nfull = pcnt / 25;
            const int* sxp = sx + pl;
            for (int kk = 0; kk < nfull; ++kk) {
                int u = sxp[kk * 25];                // LDS broadcast (10 lanes share)
                *outp = sW4[u * 10 + c];
                outp += 250;
            }
            const int rem = pcnt - nfull * 25;
            if (pl < rem) {
                int u = sxp[nfull * 25];
                *outp = sW4[u * 10 + c];
            }
        }
    }
}

extern "C" void kernel_launch(void* const* d_in, const int* in_sizes, int n_in,
                              void* d_out, int out_size, void* d_ws, size_t ws_size,
                              hipStream_t stream) {
    const int* x = (const int*)d_in[0];        // [256,4096] int32
    const float* W = (const float*)d_in[1];    // [101,40] f32
    float* out = (float*)d_out;

    fused_kernel<<<NBLK, 256, 0, stream>>>(x, W, out);
}